// Round 4
// baseline (386.260 us; speedup 1.0000x reference)
//
#include <hip/hip_runtime.h>

// r = 1 - cov(x,y)/sqrt(|var(x)*var(y)|) per row (cov identity for
// 0.5*(var(x+y)-var(x)-var(y))), then mean over 768 rows.
// Pass 1: 5 sufficient stats (Sx,Sy,Sxx,Syy,Sxy) per (row,chunk) block.
// Pass 2: single block combines chunks -> per-row r -> mean.
//
// R3 lessons: deep load batches (16 float4 in flight before any use) fixed
// the latency serialization (130 -> ~100 us). But nontemporal loads defeat
// the L3: the harness's input-restore re-warms the 256 MiB LLC each
// iteration, so ~50% of the 402 MB footprint is an L3 hit (R2 FETCH_SIZE
// = 201 MB). Plain loads keep that path. // do NOT re-add NT loads here.

#define ROWS 768          // 8*16*6
#define ROW_ELEMS 65536   // 256*256
#define BLOCK 256
#define SPLIT 4                         // chunks per row
#define NBLK (ROWS * SPLIT)             // 3072 partial blocks

typedef float f4 __attribute__((ext_vector_type(4)));

__global__ __launch_bounds__(BLOCK, 4) void partial_kernel(const float* __restrict__ x,
                                                           const float* __restrict__ y,
                                                           float* __restrict__ part) {
    const int blk = blockIdx.x;          // row*SPLIT + chunk
    const size_t base = (size_t)blk * (ROW_ELEMS / SPLIT);
    const f4* __restrict__ x4 = (const f4*)(x + base);
    const f4* __restrict__ y4 = (const f4*)(y + base);
    const int tid = threadIdx.x;

    f4 vsx = {0.f, 0.f, 0.f, 0.f};
    f4 vsy = {0.f, 0.f, 0.f, 0.f};
    f4 vsxx = {0.f, 0.f, 0.f, 0.f};
    f4 vsyy = {0.f, 0.f, 0.f, 0.f};
    f4 vsxy = {0.f, 0.f, 0.f, 0.f};

    // 4096 f4 per chunk / 256 threads = 16 f4/thread = 2 superbatches of
    // (8 x-f4 + 8 y-f4). All 16 loads issued before any consumption.
    #pragma unroll
    for (int it = 0; it < 2; ++it) {
        const int i = tid + it * (BLOCK * 8);
        f4 a[8], b[8];
        #pragma unroll
        for (int j = 0; j < 8; ++j)
            a[j] = x4[i + j * BLOCK];
        #pragma unroll
        for (int j = 0; j < 8; ++j)
            b[j] = y4[i + j * BLOCK];
        #pragma unroll
        for (int j = 0; j < 8; ++j) {
            vsx  += a[j];
            vsy  += b[j];
            vsxx += a[j] * a[j];
            vsyy += b[j] * b[j];
            vsxy += a[j] * b[j];
        }
    }

    // horizontal reduce vector accumulators to scalars
    float sx  = vsx.x  + vsx.y  + vsx.z  + vsx.w;
    float sy  = vsy.x  + vsy.y  + vsy.z  + vsy.w;
    float sxx = vsxx.x + vsxx.y + vsxx.z + vsxx.w;
    float syy = vsyy.x + vsyy.y + vsyy.z + vsyy.w;
    float sxy = vsxy.x + vsxy.y + vsxy.z + vsxy.w;

    // 64-lane wave shuffle reduction
    #pragma unroll
    for (int off = 32; off > 0; off >>= 1) {
        sx  += __shfl_down(sx,  off);
        sy  += __shfl_down(sy,  off);
        sxx += __shfl_down(sxx, off);
        syy += __shfl_down(syy, off);
        sxy += __shfl_down(sxy, off);
    }

    __shared__ float sm[5][BLOCK / 64];
    const int wave = tid >> 6;
    const int lane = tid & 63;
    if (lane == 0) {
        sm[0][wave] = sx;  sm[1][wave] = sy;
        sm[2][wave] = sxx; sm[3][wave] = syy;
        sm[4][wave] = sxy;
    }
    __syncthreads();

    if (tid == 0) {
        float t0 = 0.f, t1 = 0.f, t2 = 0.f, t3 = 0.f, t4 = 0.f;
        #pragma unroll
        for (int w = 0; w < BLOCK / 64; ++w) {
            t0 += sm[0][w]; t1 += sm[1][w];
            t2 += sm[2][w]; t3 += sm[3][w];
            t4 += sm[4][w];
        }
        // struct-of-arrays for coalesced reads in pass 2
        part[0 * NBLK + blk] = t0;
        part[1 * NBLK + blk] = t1;
        part[2 * NBLK + blk] = t2;
        part[3 * NBLK + blk] = t3;
        part[4 * NBLK + blk] = t4;
    }
}

__global__ __launch_bounds__(BLOCK) void finalize_kernel(const float* __restrict__ part,
                                                         float* __restrict__ out) {
    float acc = 0.f;
    for (int row = threadIdx.x; row < ROWS; row += BLOCK) {
        float tsx = 0.f, tsy = 0.f, tsxx = 0.f, tsyy = 0.f, tsxy = 0.f;
        #pragma unroll
        for (int c = 0; c < SPLIT; ++c) {
            const int b = row * SPLIT + c;
            tsx  += part[0 * NBLK + b];
            tsy  += part[1 * NBLK + b];
            tsxx += part[2 * NBLK + b];
            tsyy += part[3 * NBLK + b];
            tsxy += part[4 * NBLK + b];
        }
        const float n = (float)ROW_ELEMS;
        const float inv_nm1 = 1.0f / (n - 1.0f);
        float vx  = (tsxx - tsx * tsx / n) * inv_nm1;
        float vy  = (tsyy - tsy * tsy / n) * inv_nm1;
        float cov = (tsxy - tsx * tsy / n) * inv_nm1;
        acc += 1.0f - cov / sqrtf(fabsf(vx * vy));
    }

    #pragma unroll
    for (int off = 32; off > 0; off >>= 1) acc += __shfl_down(acc, off);

    __shared__ float sm[BLOCK / 64];
    const int wave = threadIdx.x >> 6;
    const int lane = threadIdx.x & 63;
    if (lane == 0) sm[wave] = acc;
    __syncthreads();

    if (threadIdx.x == 0) {
        float t = 0.f;
        #pragma unroll
        for (int w = 0; w < BLOCK / 64; ++w) t += sm[w];
        out[0] = t / (float)ROWS;
    }
}

extern "C" void kernel_launch(void* const* d_in, const int* in_sizes, int n_in,
                              void* d_out, int out_size, void* d_ws, size_t ws_size,
                              hipStream_t stream) {
    const float* x = (const float*)d_in[0];
    const float* y = (const float*)d_in[1];
    float* part = (float*)d_ws;   // 5 * 3072 floats = 60 KB scratch
    float* out = (float*)d_out;

    partial_kernel<<<NBLK, BLOCK, 0, stream>>>(x, y, part);
    finalize_kernel<<<1, BLOCK, 0, stream>>>(part, out);
}